// Round 6
// baseline (991.388 us; speedup 1.0000x reference)
//
#include <hip/hip_runtime.h>
#include <hip/hip_bf16.h>

// ---------------------------------------------------------------------------
// GNN: hiddens = relu(gcn(x,W1,b1)); emb = gcn(hiddens,W2,b2);
// pred_i/j = <emb[r,y,:],emb[c,y,:]> at head y[r]/y[c].
//
// aggregate-then-transform: A_norm @ (H @ W) = (A_norm @ H) @ W.
// Normalization refactor: agg[d] = dinv[d]*( sum_e feat_scaled[src] +
//   feat_scaled[d] ), feat_scaled[i] = dinv[i]*feat[i]. So CSR needs ONLY
//   src (4B/edge), fill does no dinv gathers, agg inner loop is pure adds.
// CSR build: count -> 3-phase scan -> fill (src only).
// agg: wave/node, two contiguous 32-lane edge groups, 8 gathers in flight,
//      writes bf16 hi/lo (split hoisted out of GEMM).
// GEMM: split-bf16 MFMA (C = Ah*Bh + Ah*Bl + Al*Bh, fp32 accumulate).
//   128x128 tile, 4 waves (2x2), wave tile 64x64 = 4x4 frags of 16x16x32.
//   BK=64 x 2 phases, 64KB LDS -> 2 blocks/CU. gemm1 epilogue also emits
//   hs = hiddens*dinv (pre-scaled input for layer-2 agg).
// ---------------------------------------------------------------------------

#define SCAN_SEG 512   // elements per scan block (256 threads x 2)

typedef short bf16x8 __attribute__((ext_vector_type(8)));   // 8 bf16 in 4 VGPRs
typedef float f32x4  __attribute__((ext_vector_type(4)));

__device__ __forceinline__ ushort f2bf(float x) {           // truncate: lo term catches residual
    return (ushort)(__float_as_uint(x) >> 16);
}
__device__ __forceinline__ float bf2f(ushort h) {
    return __uint_as_float(((unsigned)h) << 16);
}

__global__ void count_kernel(const int* __restrict__ dst, int* __restrict__ cnt, int E) {
    int e = blockIdx.x * blockDim.x + threadIdx.x;
    if (e < E) atomicAdd(&cnt[dst[e]], 1);
}

// phase 1: per-block segment sums (coalesced)
__global__ __launch_bounds__(256) void blocksum_kernel(const int* __restrict__ cnt,
                                                       int* __restrict__ blocksum, int n) {
    __shared__ int red[4];
    int b = blockIdx.x, t = threadIdx.x;
    int i0 = b * SCAN_SEG + t;
    int s = 0;
    if (i0 < n) s += cnt[i0];
    if (i0 + 256 < n) s += cnt[i0 + 256];
#pragma unroll
    for (int off = 32; off >= 1; off >>= 1) s += __shfl_xor(s, off, 64);
    if ((t & 63) == 0) red[t >> 6] = s;
    __syncthreads();
    if (t == 0) blocksum[b] = red[0] + red[1] + red[2] + red[3];
}

// phase 2: exclusive scan of <=256 block sums in one small block
__global__ __launch_bounds__(256) void blockscan_kernel(const int* __restrict__ blocksum,
                                                        int* __restrict__ blockoff, int nb,
                                                        int* __restrict__ row_ptr, int n, int E) {
    __shared__ int s[256];
    int t = threadIdx.x;
    int v = (t < nb) ? blocksum[t] : 0;
    s[t] = v;
    __syncthreads();
    for (int off = 1; off < 256; off <<= 1) {
        int u = (t >= off) ? s[t - off] : 0;
        __syncthreads();
        s[t] += u;
        __syncthreads();
    }
    if (t < nb) blockoff[t] = s[t] - v;   // exclusive
    if (t == 0) row_ptr[n] = E;
}

// phase 3: per-block exclusive scan over its 512-elem segment -> row_ptr/cursor/dinv
__global__ __launch_bounds__(256) void csr_ptr_kernel(const int* __restrict__ cnt,
                                                      const int* __restrict__ blockoff,
                                                      int* __restrict__ row_ptr,
                                                      int* __restrict__ cursor,
                                                      float* __restrict__ dinv, int n) {
    __shared__ int s[256];
    int b = blockIdx.x, t = threadIdx.x;
    int i0 = b * SCAN_SEG + 2 * t;       // thread handles i0, i0+1
    int c0 = (i0     < n) ? cnt[i0]     : 0;
    int c1 = (i0 + 1 < n) ? cnt[i0 + 1] : 0;
    int pair = c0 + c1;
    s[t] = pair;
    __syncthreads();
    for (int off = 1; off < 256; off <<= 1) {
        int u = (t >= off) ? s[t - off] : 0;
        __syncthreads();
        s[t] += u;
        __syncthreads();
    }
    int excl = s[t] - pair + blockoff[b];
    if (i0 < n) {
        row_ptr[i0] = excl;
        cursor[i0]  = excl;
        dinv[i0]    = rsqrtf((float)(c0 + 1));
    }
    if (i0 + 1 < n) {
        row_ptr[i0 + 1] = excl + c0;
        cursor[i0 + 1]  = excl + c0;
        dinv[i0 + 1]    = rsqrtf((float)(c1 + 1));
    }
}

// fill: src index only (weights are implicit via pre-scaled features)
__global__ void fill_kernel(const int* __restrict__ src, const int* __restrict__ dst,
                            int* __restrict__ cursor, int* __restrict__ csr_src, int E) {
    int e = blockIdx.x * blockDim.x + threadIdx.x;
    if (e < E) {
        int d = dst[e];
        int pos = atomicAdd(&cursor[d], 1);
        csr_src[pos] = src[e];
    }
}

// xs[i,f] = x[i,f] * dinv[i]   (float4-vectorized, 32 float4 per row)
__global__ __launch_bounds__(256) void prescale_kernel(const float* __restrict__ x,
                                                       const float* __restrict__ dinv,
                                                       float* __restrict__ xs, int n) {
    int id = blockIdx.x * 256 + threadIdx.x;   // float4 index
    if (id >= n * 32) return;
    int row = id >> 5;
    float di = dinv[row];
    float4 v = ((const float4*)x)[id];
    v.x *= di; v.y *= di; v.z *= di; v.w *= di;
    ((float4*)xs)[id] = v;
}

// W[k][ncols] fp32 -> Wt_h/Wt_l[col][k] bf16 hi/lo (transposed, split). Tiny, once.
__global__ __launch_bounds__(256) void wsplit_kernel(const float* __restrict__ W,
                                                     ushort* __restrict__ th,
                                                     ushort* __restrict__ tl, int ncols) {
    int idx = blockIdx.x * 256 + threadIdx.x;   // over 128*ncols
    if (idx >= 128 * ncols) return;
    int col = idx >> 7;
    int k   = idx & 127;
    float v = W[(size_t)k * ncols + col];
    ushort h = f2bf(v);
    th[idx] = h;
    tl[idx] = f2bf(v - bf2f(h));
}

// agg: out_{h,l}[node,f] = split( dinv[node] * ( feat[node,f] + sum_e feat[src[e],f] ) )
// feat is PRE-SCALED (feat_scaled = dinv*raw). One wave per node; two
// contiguous 32-lane edge half-ranges; 8 row-gathers in flight.
__global__ __launch_bounds__(256) void agg_kernel(const float* __restrict__ feat,
                                                  const int* __restrict__ row_ptr,
                                                  const int* __restrict__ csr_src,
                                                  const float* __restrict__ dinv,
                                                  ushort* __restrict__ outh,
                                                  ushort* __restrict__ outl, int n) {
    const int w    = threadIdx.x >> 6;         // wave 0..3
    const int lane = threadIdx.x & 63;
    const int node = blockIdx.x * 4 + w;
    if (node >= n) return;
    const int g = lane >> 5;                   // half-range group 0/1
    const int c = lane & 31;                   // float4 column index (covers 128 feats)

    const float di = dinv[node];
    float4 acc0 = make_float4(0.f, 0.f, 0.f, 0.f);
    float4 acc1 = make_float4(0.f, 0.f, 0.f, 0.f);
    if (g == 0)                                // self-loop message (pre-scaled)
        acc0 = ((const float4*)(feat + (size_t)node * 128))[c];

    const int e0 = row_ptr[node], e1 = row_ptr[node + 1];
    const int half = (e1 - e0 + 1) >> 1;
    int e  = e0 + (g ? half : 0);
    const int ge = g ? e1 : e0 + half;

    for (; e + 7 < ge; e += 8) {               // 8 gathers in flight
        int s0 = csr_src[e],     s1 = csr_src[e + 1];
        int s2 = csr_src[e + 2], s3 = csr_src[e + 3];
        int s4 = csr_src[e + 4], s5 = csr_src[e + 5];
        int s6 = csr_src[e + 6], s7 = csr_src[e + 7];
        float4 v0 = ((const float4*)(feat + (size_t)s0 * 128))[c];
        float4 v1 = ((const float4*)(feat + (size_t)s1 * 128))[c];
        float4 v2 = ((const float4*)(feat + (size_t)s2 * 128))[c];
        float4 v3 = ((const float4*)(feat + (size_t)s3 * 128))[c];
        float4 v4 = ((const float4*)(feat + (size_t)s4 * 128))[c];
        float4 v5 = ((const float4*)(feat + (size_t)s5 * 128))[c];
        float4 v6 = ((const float4*)(feat + (size_t)s6 * 128))[c];
        float4 v7 = ((const float4*)(feat + (size_t)s7 * 128))[c];
        acc0.x += v0.x + v2.x + v4.x + v6.x;  acc1.x += v1.x + v3.x + v5.x + v7.x;
        acc0.y += v0.y + v2.y + v4.y + v6.y;  acc1.y += v1.y + v3.y + v5.y + v7.y;
        acc0.z += v0.z + v2.z + v4.z + v6.z;  acc1.z += v1.z + v3.z + v5.z + v7.z;
        acc0.w += v0.w + v2.w + v4.w + v6.w;  acc1.w += v1.w + v3.w + v5.w + v7.w;
    }
    for (; e + 1 < ge; e += 2) {
        int s0 = csr_src[e], s1 = csr_src[e + 1];
        float4 v0 = ((const float4*)(feat + (size_t)s0 * 128))[c];
        float4 v1 = ((const float4*)(feat + (size_t)s1 * 128))[c];
        acc0.x += v0.x; acc1.x += v1.x;
        acc0.y += v0.y; acc1.y += v1.y;
        acc0.z += v0.z; acc1.z += v1.z;
        acc0.w += v0.w; acc1.w += v1.w;
    }
    if (e < ge) {
        int s0 = csr_src[e];
        float4 v0 = ((const float4*)(feat + (size_t)s0 * 128))[c];
        acc0.x += v0.x; acc0.y += v0.y; acc0.z += v0.z; acc0.w += v0.w;
    }
    acc0.x += acc1.x; acc0.y += acc1.y; acc0.z += acc1.z; acc0.w += acc1.w;

    // combine the two half-range groups
    acc0.x += __shfl_xor(acc0.x, 32, 64);
    acc0.y += __shfl_xor(acc0.y, 32, 64);
    acc0.z += __shfl_xor(acc0.z, 32, 64);
    acc0.w += __shfl_xor(acc0.w, 32, 64);

    if (g == 0) {
        acc0.x *= di; acc0.y *= di; acc0.z *= di; acc0.w *= di;
        ushort4 h, l;
        h.x = f2bf(acc0.x); l.x = f2bf(acc0.x - bf2f(h.x));
        h.y = f2bf(acc0.y); l.y = f2bf(acc0.y - bf2f(h.y));
        h.z = f2bf(acc0.z); l.z = f2bf(acc0.z - bf2f(h.z));
        h.w = f2bf(acc0.w); l.w = f2bf(acc0.w - bf2f(h.w));
        *(ushort4*)(outh + (size_t)node * 128 + c * 4) = h;
        *(ushort4*)(outl + (size_t)node * 128 + c * 4) = l;
    }
}

// ---------------------------------------------------------------------------
// C[N, 128-col chunk] = X @ W + bias (split-bf16 MFMA), inputs pre-split:
//   Xh/Xl: [N][128] bf16 row-major; Wth/Wtl: [colG][128] bf16 (pre-transposed).
// LDS per half-K: [row|col 0..127][k 0..63] bf16, 16B-chunk XOR swizzle
//   byte ^ ((row&7)<<4), both write and read sides.
// Fragment maps (mfma_f32_16x16x32_bf16):
//   A: row=lane&15, k=(lane>>4)*8+j ; B: col=lane&15, same k
//   C/D: col=lane&15, row=(lane>>4)*4+reg   [guide m89-verified]
// If hs != nullptr (layer 1, ldw==128): also write hs = result * dinv[row].
// ---------------------------------------------------------------------------
__global__ __launch_bounds__(256, 2) void gemm_mfma(const ushort* __restrict__ Xh_g,
                                                    const ushort* __restrict__ Xl_g,
                                                    const ushort* __restrict__ Wth_g,
                                                    const ushort* __restrict__ Wtl_g,
                                                    const float* __restrict__ bias,
                                                    float* __restrict__ C,
                                                    float* __restrict__ hs,
                                                    const float* __restrict__ dinvp,
                                                    int N, int ldw, int do_relu) {
    __shared__ ushort Xh[128 * 64];   // 16 KB each, 64 KB total -> 2 blocks/CU
    __shared__ ushort Xl[128 * 64];
    __shared__ ushort Wh[128 * 64];
    __shared__ ushort Wl[128 * 64];

    const int tid  = threadIdx.x;
    const int lane = tid & 63;
    const int wv   = tid >> 6;        // wave 0..3
    const int wr   = wv >> 1;         // wave row 0..1 (64 rows each)
    const int wc   = wv & 1;          // wave col 0..1 (64 cols each)
    const int lr   = lane & 15;
    const int lk   = lane >> 4;       // k-group 0..3
    const int row0   = blockIdx.y * 128;
    const int colOff = blockIdx.x * 128;

    f32x4 acc[4][4];
#pragma unroll
    for (int i = 0; i < 4; ++i)
#pragma unroll
        for (int j = 0; j < 4; ++j)
            acc[i][j] = (f32x4){0.f, 0.f, 0.f, 0.f};

    for (int ph = 0; ph < 2; ++ph) {
        if (ph) __syncthreads();      // prev compute done before overwrite

        // ---- stage X half-tile: pure swizzled 16B copies ----
#pragma unroll
        for (int q = 0; q < 4; ++q) {
            int cidx = tid + 256 * q;            // 16B-chunk id 0..1023
            int row  = cidx >> 3;                // 0..127
            int kch  = cidx & 7;                 // 16B chunk within 64-k half
            int gr   = row0 + row; if (gr >= N) gr = N - 1;
            size_t ge = (size_t)gr * 128 + ph * 64 + kch * 8;
            int lb = row * 128 + ((kch * 16) ^ ((row & 7) << 4));
            *(int4*)((char*)Xh + lb) = *(const int4*)(Xh_g + ge);
            *(int4*)((char*)Xl + lb) = *(const int4*)(Xl_g + ge);
        }
        // ---- stage W half-tile (already transposed/split in global) ----
#pragma unroll
        for (int q = 0; q < 4; ++q) {
            int cidx = tid + 256 * q;
            int col  = cidx >> 3;
            int kch  = cidx & 7;
            size_t ge = (size_t)(colOff + col) * 128 + ph * 64 + kch * 8;
            int lb = col * 128 + ((kch * 16) ^ ((col & 7) << 4));
            *(int4*)((char*)Wh + lb) = *(const int4*)(Wth_g + ge);
            *(int4*)((char*)Wl + lb) = *(const int4*)(Wtl_g + ge);
        }
        __syncthreads();

        // ---- compute: 2 x K=32 chunks per phase ----
#pragma unroll
        for (int kk = 0; kk < 2; ++kk) {
            const int kb2 = (kk * 32 + lk * 8) * 2;   // byte offset pre-swizzle
            bf16x8 ah[4], al[4], bh[4], bl[4];
#pragma unroll
            for (int mi = 0; mi < 4; ++mi) {
                int row  = wr * 64 + mi * 16 + lr;
                int byte = row * 128 + (kb2 ^ ((row & 7) << 4));
                ah[mi] = *(const bf16x8*)((const char*)Xh + byte);
                al[mi] = *(const bf16x8*)((const char*)Xl + byte);
            }
#pragma unroll
            for (int ni = 0; ni < 4; ++ni) {
                int col  = wc * 64 + ni * 16 + lr;
                int byte = col * 128 + (kb2 ^ ((col & 7) << 4));
                bh[ni] = *(const bf16x8*)((const char*)Wh + byte);
                bl[ni] = *(const bf16x8*)((const char*)Wl + byte);
            }
#pragma unroll
            for (int mi = 0; mi < 4; ++mi)
#pragma unroll
                for (int ni = 0; ni < 4; ++ni) {
                    acc[mi][ni] = __builtin_amdgcn_mfma_f32_16x16x32_bf16(
                        ah[mi], bh[ni], acc[mi][ni], 0, 0, 0);
                    acc[mi][ni] = __builtin_amdgcn_mfma_f32_16x16x32_bf16(
                        ah[mi], bl[ni], acc[mi][ni], 0, 0, 0);
                    acc[mi][ni] = __builtin_amdgcn_mfma_f32_16x16x32_bf16(
                        al[mi], bh[ni], acc[mi][ni], 0, 0, 0);
                }
        }
    }

    // ---- epilogue: bias (+relu), scalar stores (64B/quarter-wave segments) ----
#pragma unroll
    for (int ni = 0; ni < 4; ++ni) {
        int col = colOff + wc * 64 + ni * 16 + lr;
        float bv = bias[col];
#pragma unroll
        for (int mi = 0; mi < 4; ++mi) {
            int rbase = row0 + wr * 64 + mi * 16 + (lane >> 4) * 4;
#pragma unroll
            for (int r = 0; r < 4; ++r) {
                int row = rbase + r;
                if (row < N) {
                    float v = acc[mi][ni][r] + bv;
                    if (do_relu) v = fmaxf(v, 0.f);
                    C[(size_t)row * ldw + col] = v;
                    if (hs) hs[(size_t)row * 128 + col] = v * dinvp[row];
                }
            }
        }
    }
}

// one wave per query edge; 4 lane-groups of 16 gather the 4 head-vectors in
// ONE float4 issue; shfl_xor(16) pairs er*ec; 16-lane reduce; shfl_xor(32)
// marries pi (lanes 0..31) with pj (lanes 32..63).
__global__ __launch_bounds__(256) void query_kernel(const float* __restrict__ emb,
                                                    const int* __restrict__ qrow,
                                                    const int* __restrict__ qcol,
                                                    const int* __restrict__ y,
                                                    float* __restrict__ pred_i,
                                                    float* __restrict__ pred_j,
                                                    float* __restrict__ pred, int Q) {
    int wave = (int)((blockIdx.x * 256 + threadIdx.x) >> 6);
    int lane = threadIdx.x & 63;
    if (wave >= Q) return;
    int r = qrow[wave], c = qcol[wave];
    int yr = y[r], yc = y[c];                  // uniform -> broadcast loads
    int g = lane >> 4;                         // 0: emb[r,yr] 1: emb[c,yr] 2: emb[r,yc] 3: emb[c,yc]
    int t = lane & 15;
    int node = (g & 1) ? c : r;
    int head = (g >> 1) ? yc : yr;
    const float4* p = (const float4*)(emb + (size_t)node * 512 + head * 64);
    float4 v = p[t];
    float4 o;
    o.x = __shfl_xor(v.x, 16, 64);
    o.y = __shfl_xor(v.y, 16, 64);
    o.z = __shfl_xor(v.z, 16, 64);
    o.w = __shfl_xor(v.w, 16, 64);
    float s = v.x * o.x + v.y * o.y + v.z * o.z + v.w * o.w;
#pragma unroll
    for (int off = 8; off >= 1; off >>= 1) s += __shfl_xor(s, off, 64);
    float other = __shfl_xor(s, 32, 64);       // lane0: pj
    if (lane == 0) {
        pred_i[wave] = s;
        pred_j[wave] = other;
        pred[wave]   = 0.5f * (s + other);
    }
}

extern "C" void kernel_launch(void* const* d_in, const int* in_sizes, int n_in,
                              void* d_out, int out_size, void* d_ws, size_t ws_size,
                              hipStream_t stream) {
    const float* x   = (const float*)d_in[0];
    const float* W1  = (const float*)d_in[1];
    const float* b1  = (const float*)d_in[2];
    const float* W2  = (const float*)d_in[3];
    const float* b2  = (const float*)d_in[4];
    const int* edge  = (const int*)d_in[5];
    const int* qedge = (const int*)d_in[6];
    const int* y     = (const int*)d_in[7];

    const int N = in_sizes[0] / 128;   // 100000
    const int E = in_sizes[5] / 2;     // 1600000
    const int Q = in_sizes[6] / 2;     // 400000

    float* out     = (float*)d_out;
    float* hiddens = out;                         // [N,128]
    float* emb     = out + (size_t)N * 128;       // [N,512]
    float* pred_i  = emb + (size_t)N * 512;       // [Q]
    float* pred_j  = pred_i + Q;                  // [Q]
    float* pred    = pred_j + Q;                  // [Q]

    // workspace carve (256B aligned)
    char* w = (char*)d_ws;
    auto alloc = [&](size_t bytes) { char* p = w; w += (bytes + 255) & ~(size_t)255; return p; };
    int*    cnt      = (int*)alloc((size_t)N * 4);
    int*    row_ptr  = (int*)alloc((size_t)(N + 1) * 4);
    int*    cursor   = (int*)alloc((size_t)N * 4);
    float*  dinv     = (float*)alloc((size_t)N * 4);
    int*    csr_src  = (int*)alloc((size_t)E * 4);            // src only (4B/edge)
    int*    blocksum = (int*)alloc(256 * 4);
    int*    blockoff = (int*)alloc(256 * 4);
    float*  scaled   = (float*)alloc((size_t)N * 128 * 4);    // xs then hs (lifetimes disjoint)
    ushort* aggh     = (ushort*)alloc((size_t)N * 128 * 2);   // 25.6 MB
    ushort* aggl     = (ushort*)alloc((size_t)N * 128 * 2);   // 25.6 MB
    ushort* w1h      = (ushort*)alloc(128 * 128 * 2);
    ushort* w1l      = (ushort*)alloc(128 * 128 * 2);
    ushort* w2h      = (ushort*)alloc(128 * 512 * 2);
    ushort* w2l      = (ushort*)alloc(128 * 512 * 2);

    const int* esrc = edge;         const int* edst = edge + E;
    const int* qrow = qedge;        const int* qcol = qedge + Q;

    const int nb = (N + SCAN_SEG - 1) / SCAN_SEG;   // 196 <= 256

    hipMemsetAsync(cnt, 0, (size_t)N * 4, stream);
    count_kernel<<<dim3((E + 255) / 256), dim3(256), 0, stream>>>(edst, cnt, E);
    blocksum_kernel<<<dim3(nb), dim3(256), 0, stream>>>(cnt, blocksum, N);
    blockscan_kernel<<<dim3(1), dim3(256), 0, stream>>>(blocksum, blockoff, nb, row_ptr, N, E);
    csr_ptr_kernel<<<dim3(nb), dim3(256), 0, stream>>>(cnt, blockoff, row_ptr, cursor, dinv, N);
    prescale_kernel<<<dim3((N * 32 + 255) / 256), dim3(256), 0, stream>>>(x, dinv, scaled, N);
    fill_kernel<<<dim3((E + 255) / 256), dim3(256), 0, stream>>>(esrc, edst, cursor, csr_src, E);

    // one-time weight transpose+split (tiny)
    wsplit_kernel<<<dim3((128 * 128 + 255) / 256), dim3(256), 0, stream>>>(W1, w1h, w1l, 128);
    wsplit_kernel<<<dim3((128 * 512 + 255) / 256), dim3(256), 0, stream>>>(W2, w2h, w2l, 512);

    const int mblocks = (N + 127) / 128;   // 782
    const int ablocks = (N + 3) / 4;       // 25000

    // layer 1: aggregate xs, then MFMA GEMM (bias+relu fused; also emits hs)
    agg_kernel<<<dim3(ablocks), dim3(256), 0, stream>>>(scaled, row_ptr, csr_src, dinv, aggh, aggl, N);
    gemm_mfma<<<dim3(1, mblocks), dim3(256), 0, stream>>>(aggh, aggl, w1h, w1l, b1, hiddens,
                                                          scaled /*hs*/, dinv, N, 128, 1);

    // layer 2: aggregate hs, then MFMA GEMM with fused bias
    agg_kernel<<<dim3(ablocks), dim3(256), 0, stream>>>(scaled, row_ptr, csr_src, dinv, aggh, aggl, N);
    gemm_mfma<<<dim3(4, mblocks), dim3(256), 0, stream>>>(aggh, aggl, w2h, w2l, b2, emb,
                                                          nullptr, nullptr, N, 512, 0);

    query_kernel<<<dim3((Q + 3) / 4), dim3(256), 0, stream>>>(emb, qrow, qcol, y, pred_i, pred_j, pred, Q);
}

// Round 7
// 840.979 us; speedup vs baseline: 1.1788x; 1.1788x over previous
//
#include <hip/hip_runtime.h>
#include <hip/hip_bf16.h>
#include <hip/hip_fp16.h>

// ---------------------------------------------------------------------------
// GNN: hiddens = relu(gcn(x,W1,b1)); emb = gcn(hiddens,W2,b2);
// pred_i/j = <emb[r,y,:],emb[c,y,:]> at head y[r]/y[c].
//
// aggregate-then-transform: A_norm @ (H @ W) = (A_norm @ H) @ W.
// CSR build: count -> 3-phase scan -> fill writes PAIRED {src, wt} int2.
// agg: wave/node, 2x32-lane interleaved edge groups, float4-equiv gathers
//      4-deep in flight (threshold deg>=8 covers ~97% of Poisson(16) nodes
//      -- round-6 lesson: 8-deep collapsed MLP for half the nodes).
//      GATHER TABLE IS FP16 (256B/row, halves gather traffic vs fp32;
//      rel err 2^-12, fp32 accumulate). Output bf16 hi/lo for the GEMM.
// GEMM: split-bf16 MFMA (C = Ah*Bh + Ah*Bl + Al*Bh, fp32 accumulate).
//   128x128 tile, 4 waves (2x2), wave tile 64x64 = 4x4 frags of 16x16x32.
//   BK=64 x 2 phases, 64KB LDS -> 2 blocks/CU. gemm1 epilogue also emits
//   the fp16 hiddens table for layer-2 agg.
// ---------------------------------------------------------------------------

#define SCAN_SEG 512   // elements per scan block (256 threads x 2)

typedef short bf16x8 __attribute__((ext_vector_type(8)));   // 8 bf16 in 4 VGPRs
typedef float f32x4  __attribute__((ext_vector_type(4)));

struct __align__(8) half4_t { __half2 a, b; };              // 4 fp16 in 8B

__device__ __forceinline__ ushort f2bf(float x) {           // truncate: lo term catches residual
    return (ushort)(__float_as_uint(x) >> 16);
}
__device__ __forceinline__ float bf2f(ushort h) {
    return __uint_as_float(((unsigned)h) << 16);
}

__global__ void count_kernel(const int* __restrict__ dst, int* __restrict__ cnt, int E) {
    int e = blockIdx.x * blockDim.x + threadIdx.x;
    if (e < E) atomicAdd(&cnt[dst[e]], 1);
}

// phase 1: per-block segment sums (coalesced)
__global__ __launch_bounds__(256) void blocksum_kernel(const int* __restrict__ cnt,
                                                       int* __restrict__ blocksum, int n) {
    __shared__ int red[4];
    int b = blockIdx.x, t = threadIdx.x;
    int i0 = b * SCAN_SEG + t;
    int s = 0;
    if (i0 < n) s += cnt[i0];
    if (i0 + 256 < n) s += cnt[i0 + 256];
#pragma unroll
    for (int off = 32; off >= 1; off >>= 1) s += __shfl_xor(s, off, 64);
    if ((t & 63) == 0) red[t >> 6] = s;
    __syncthreads();
    if (t == 0) blocksum[b] = red[0] + red[1] + red[2] + red[3];
}

// phase 2: exclusive scan of <=256 block sums in one small block
__global__ __launch_bounds__(256) void blockscan_kernel(const int* __restrict__ blocksum,
                                                        int* __restrict__ blockoff, int nb,
                                                        int* __restrict__ row_ptr, int n, int E) {
    __shared__ int s[256];
    int t = threadIdx.x;
    int v = (t < nb) ? blocksum[t] : 0;
    s[t] = v;
    __syncthreads();
    for (int off = 1; off < 256; off <<= 1) {
        int u = (t >= off) ? s[t - off] : 0;
        __syncthreads();
        s[t] += u;
        __syncthreads();
    }
    if (t < nb) blockoff[t] = s[t] - v;   // exclusive
    if (t == 0) row_ptr[n] = E;
}

// phase 3: per-block exclusive scan over its 512-elem segment -> row_ptr/cursor/dinv
__global__ __launch_bounds__(256) void csr_ptr_kernel(const int* __restrict__ cnt,
                                                      const int* __restrict__ blockoff,
                                                      int* __restrict__ row_ptr,
                                                      int* __restrict__ cursor,
                                                      float* __restrict__ dinv, int n) {
    __shared__ int s[256];
    int b = blockIdx.x, t = threadIdx.x;
    int i0 = b * SCAN_SEG + 2 * t;       // thread handles i0, i0+1
    int c0 = (i0     < n) ? cnt[i0]     : 0;
    int c1 = (i0 + 1 < n) ? cnt[i0 + 1] : 0;
    int pair = c0 + c1;
    s[t] = pair;
    __syncthreads();
    for (int off = 1; off < 256; off <<= 1) {
        int u = (t >= off) ? s[t - off] : 0;
        __syncthreads();
        s[t] += u;
        __syncthreads();
    }
    int excl = s[t] - pair + blockoff[b];
    if (i0 < n) {
        row_ptr[i0] = excl;
        cursor[i0]  = excl;
        dinv[i0]    = rsqrtf((float)(c0 + 1));
    }
    if (i0 + 1 < n) {
        row_ptr[i0 + 1] = excl + c0;
        cursor[i0 + 1]  = excl + c0;
        dinv[i0 + 1]    = rsqrtf((float)(c1 + 1));
    }
}

// fill PAIRED csr entries: one 8B store per edge
__global__ void fill_kernel(const int* __restrict__ src, const int* __restrict__ dst,
                            int* __restrict__ cursor, const float* __restrict__ dinv,
                            int2* __restrict__ csr, int E) {
    int e = blockIdx.x * blockDim.x + threadIdx.x;
    if (e < E) {
        int s = src[e], d = dst[e];
        int pos = atomicAdd(&cursor[d], 1);
        csr[pos] = make_int2(s, __float_as_int(dinv[s] * dinv[d]));
    }
}

// x fp32 [N][128] -> fp16 table (round-to-nearest)
__global__ __launch_bounds__(256) void tohalf_kernel(const float* __restrict__ x,
                                                     __half* __restrict__ xh, int n) {
    int id = blockIdx.x * 256 + threadIdx.x;   // float4 index
    if (id >= n * 32) return;
    float4 v = ((const float4*)x)[id];
    half4_t h;
    h.a = __float22half2_rn(make_float2(v.x, v.y));
    h.b = __float22half2_rn(make_float2(v.z, v.w));
    ((half4_t*)xh)[id] = h;
}

// W[k][ncols] fp32 -> Wt_h/Wt_l[col][k] bf16 hi/lo (transposed, split). Tiny, once.
__global__ __launch_bounds__(256) void wsplit_kernel(const float* __restrict__ W,
                                                     ushort* __restrict__ th,
                                                     ushort* __restrict__ tl, int ncols) {
    int idx = blockIdx.x * 256 + threadIdx.x;   // over 128*ncols
    if (idx >= 128 * ncols) return;
    int col = idx >> 7;
    int k   = idx & 127;
    float v = W[(size_t)k * ncols + col];
    ushort h = f2bf(v);
    th[idx] = h;
    tl[idx] = f2bf(v - bf2f(h));
}

// agg: out_{h,l}[node,f] = split( dinv^2*feat[node,f] + sum_e wt[e]*feat[src[e],f] )
// feat is the FP16 table (256B/row). One wave per node; two 32-lane groups
// own alternate edges (interleaved); 4 gathers in flight per group.
__global__ __launch_bounds__(256) void agg_kernel(const __half* __restrict__ feat,
                                                  const int* __restrict__ row_ptr,
                                                  const int2* __restrict__ csr,
                                                  const float* __restrict__ dinv,
                                                  ushort* __restrict__ outh,
                                                  ushort* __restrict__ outl, int n) {
    const int w    = threadIdx.x >> 6;         // wave 0..3
    const int lane = threadIdx.x & 63;
    const int node = blockIdx.x * 4 + w;
    if (node >= n) return;
    const int g = lane >> 5;                   // edge-parity group 0/1
    const int c = lane & 31;                   // 4-feat chunk index (covers 128 feats)

    float di = dinv[node];
    float4 acc = make_float4(0.f, 0.f, 0.f, 0.f);
    if (g == 0) {                              // self-loop message
        half4_t v = ((const half4_t*)(feat + (size_t)node * 128))[c];
        float2 f0 = __half22float2(v.a), f1 = __half22float2(v.b);
        float s2 = di * di;
        acc.x = f0.x * s2; acc.y = f0.y * s2; acc.z = f1.x * s2; acc.w = f1.y * s2;
    }

    int e0 = row_ptr[node], e1 = row_ptr[node + 1];
    int e = e0 + g;
    for (; e + 6 < e1; e += 8) {               // 4 edges per group in flight
        int2 p0 = csr[e],     p1 = csr[e + 2];
        int2 p2 = csr[e + 4], p3 = csr[e + 6];
        float w0 = __int_as_float(p0.y), w1 = __int_as_float(p1.y);
        float w2 = __int_as_float(p2.y), w3 = __int_as_float(p3.y);
        half4_t v0 = ((const half4_t*)(feat + (size_t)p0.x * 128))[c];
        half4_t v1 = ((const half4_t*)(feat + (size_t)p1.x * 128))[c];
        half4_t v2 = ((const half4_t*)(feat + (size_t)p2.x * 128))[c];
        half4_t v3 = ((const half4_t*)(feat + (size_t)p3.x * 128))[c];
        float2 a0 = __half22float2(v0.a), b0 = __half22float2(v0.b);
        float2 a1 = __half22float2(v1.a), b1 = __half22float2(v1.b);
        float2 a2 = __half22float2(v2.a), b2 = __half22float2(v2.b);
        float2 a3 = __half22float2(v3.a), b3 = __half22float2(v3.b);
        acc.x += a0.x * w0 + a1.x * w1 + a2.x * w2 + a3.x * w3;
        acc.y += a0.y * w0 + a1.y * w1 + a2.y * w2 + a3.y * w3;
        acc.z += b0.x * w0 + b1.x * w1 + b2.x * w2 + b3.x * w3;
        acc.w += b0.y * w0 + b1.y * w1 + b2.y * w2 + b3.y * w3;
    }
    for (; e < e1; e += 2) {
        int2 p0 = csr[e];
        float w0 = __int_as_float(p0.y);
        half4_t v0 = ((const half4_t*)(feat + (size_t)p0.x * 128))[c];
        float2 a0 = __half22float2(v0.a), b0 = __half22float2(v0.b);
        acc.x += a0.x * w0; acc.y += a0.y * w0; acc.z += b0.x * w0; acc.w += b0.y * w0;
    }

    // combine the two edge groups
    acc.x += __shfl_xor(acc.x, 32, 64);
    acc.y += __shfl_xor(acc.y, 32, 64);
    acc.z += __shfl_xor(acc.z, 32, 64);
    acc.w += __shfl_xor(acc.w, 32, 64);

    if (g == 0) {
        ushort4 h, l;
        h.x = f2bf(acc.x); l.x = f2bf(acc.x - bf2f(h.x));
        h.y = f2bf(acc.y); l.y = f2bf(acc.y - bf2f(h.y));
        h.z = f2bf(acc.z); l.z = f2bf(acc.z - bf2f(h.z));
        h.w = f2bf(acc.w); l.w = f2bf(acc.w - bf2f(h.w));
        *(ushort4*)(outh + (size_t)node * 128 + c * 4) = h;
        *(ushort4*)(outl + (size_t)node * 128 + c * 4) = l;
    }
}

// ---------------------------------------------------------------------------
// C[N, 128-col chunk] = X @ W + bias (split-bf16 MFMA), inputs pre-split:
//   Xh/Xl: [N][128] bf16 row-major; Wth/Wtl: [colG][128] bf16 (pre-transposed).
// LDS per half-K: [row|col 0..127][k 0..63] bf16, 16B-chunk XOR swizzle
//   byte ^ ((row&7)<<4), both write and read sides.
// Fragment maps (mfma_f32_16x16x32_bf16):
//   A: row=lane&15, k=(lane>>4)*8+j ; B: col=lane&15, same k
//   C/D: col=lane&15, row=(lane>>4)*4+reg   [guide m89-verified]
// If tbl != nullptr (layer 1, ldw==128): also write fp16 table of the result.
// ---------------------------------------------------------------------------
__global__ __launch_bounds__(256, 2) void gemm_mfma(const ushort* __restrict__ Xh_g,
                                                    const ushort* __restrict__ Xl_g,
                                                    const ushort* __restrict__ Wth_g,
                                                    const ushort* __restrict__ Wtl_g,
                                                    const float* __restrict__ bias,
                                                    float* __restrict__ C,
                                                    __half* __restrict__ tbl,
                                                    int N, int ldw, int do_relu) {
    __shared__ ushort Xh[128 * 64];   // 16 KB each, 64 KB total -> 2 blocks/CU
    __shared__ ushort Xl[128 * 64];
    __shared__ ushort Wh[128 * 64];
    __shared__ ushort Wl[128 * 64];

    const int tid  = threadIdx.x;
    const int lane = tid & 63;
    const int wv   = tid >> 6;        // wave 0..3
    const int wr   = wv >> 1;         // wave row 0..1 (64 rows each)
    const int wc   = wv & 1;          // wave col 0..1 (64 cols each)
    const int lr   = lane & 15;
    const int lk   = lane >> 4;       // k-group 0..3
    const int row0   = blockIdx.y * 128;
    const int colOff = blockIdx.x * 128;

    f32x4 acc[4][4];
#pragma unroll
    for (int i = 0; i < 4; ++i)
#pragma unroll
        for (int j = 0; j < 4; ++j)
            acc[i][j] = (f32x4){0.f, 0.f, 0.f, 0.f};

    for (int ph = 0; ph < 2; ++ph) {
        if (ph) __syncthreads();      // prev compute done before overwrite

        // ---- stage X half-tile: pure swizzled 16B copies ----
#pragma unroll
        for (int q = 0; q < 4; ++q) {
            int cidx = tid + 256 * q;            // 16B-chunk id 0..1023
            int row  = cidx >> 3;                // 0..127
            int kch  = cidx & 7;                 // 16B chunk within 64-k half
            int gr   = row0 + row; if (gr >= N) gr = N - 1;
            size_t ge = (size_t)gr * 128 + ph * 64 + kch * 8;
            int lb = row * 128 + ((kch * 16) ^ ((row & 7) << 4));
            *(int4*)((char*)Xh + lb) = *(const int4*)(Xh_g + ge);
            *(int4*)((char*)Xl + lb) = *(const int4*)(Xl_g + ge);
        }
        // ---- stage W half-tile (already transposed/split in global) ----
#pragma unroll
        for (int q = 0; q < 4; ++q) {
            int cidx = tid + 256 * q;
            int col  = cidx >> 3;
            int kch  = cidx & 7;
            size_t ge = (size_t)(colOff + col) * 128 + ph * 64 + kch * 8;
            int lb = col * 128 + ((kch * 16) ^ ((col & 7) << 4));
            *(int4*)((char*)Wh + lb) = *(const int4*)(Wth_g + ge);
            *(int4*)((char*)Wl + lb) = *(const int4*)(Wtl_g + ge);
        }
        __syncthreads();

        // ---- compute: 2 x K=32 chunks per phase ----
#pragma unroll
        for (int kk = 0; kk < 2; ++kk) {
            const int kb2 = (kk * 32 + lk * 8) * 2;   // byte offset pre-swizzle
            bf16x8 ah[4], al[4], bh[4], bl[4];
#pragma unroll
            for (int mi = 0; mi < 4; ++mi) {
                int row  = wr * 64 + mi * 16 + lr;
                int byte = row * 128 + (kb2 ^ ((row & 7) << 4));
                ah[mi] = *(const bf16x8*)((const char*)Xh + byte);
                al[mi] = *(const bf16x8*)((const char*)Xl + byte);
            }
#pragma unroll
            for (int ni = 0; ni < 4; ++ni) {
                int col  = wc * 64 + ni * 16 + lr;
                int byte = col * 128 + (kb2 ^ ((col & 7) << 4));
                bh[ni] = *(const bf16x8*)((const char*)Wh + byte);
                bl[ni] = *(const bf16x8*)((const char*)Wl + byte);
            }
#pragma unroll
            for (int mi = 0; mi < 4; ++mi)
#pragma unroll
                for (int ni = 0; ni < 4; ++ni) {
                    acc[mi][ni] = __builtin_amdgcn_mfma_f32_16x16x32_bf16(
                        ah[mi], bh[ni], acc[mi][ni], 0, 0, 0);
                    acc[mi][ni] = __builtin_amdgcn_mfma_f32_16x16x32_bf16(
                        ah[mi], bl[ni], acc[mi][ni], 0, 0, 0);
                    acc[mi][ni] = __builtin_amdgcn_mfma_f32_16x16x32_bf16(
                        al[mi], bh[ni], acc[mi][ni], 0, 0, 0);
                }
        }
    }

    // ---- epilogue: bias (+relu), scalar stores (64B/quarter-wave segments) ----
#pragma unroll
    for (int ni = 0; ni < 4; ++ni) {
        int col = colOff + wc * 64 + ni * 16 + lr;
        float bv = bias[col];
#pragma unroll
        for (int mi = 0; mi < 4; ++mi) {
            int rbase = row0 + wr * 64 + mi * 16 + (lane >> 4) * 4;
#pragma unroll
            for (int r = 0; r < 4; ++r) {
                int row = rbase + r;
                if (row < N) {
                    float v = acc[mi][ni][r] + bv;
                    if (do_relu) v = fmaxf(v, 0.f);
                    C[(size_t)row * ldw + col] = v;
                    if (tbl) tbl[(size_t)row * 128 + col] = __float2half(v);
                }
            }
        }
    }
}

// one wave per query edge; 4 lane-groups of 16 gather the 4 head-vectors in
// ONE float4 issue; shfl_xor(16) pairs er*ec; 16-lane reduce; shfl_xor(32)
// marries pi (lanes 0..31) with pj (lanes 32..63).
__global__ __launch_bounds__(256) void query_kernel(const float* __restrict__ emb,
                                                    const int* __restrict__ qrow,
                                                    const int* __restrict__ qcol,
                                                    const int* __restrict__ y,
                                                    float* __restrict__ pred_i,
                                                    float* __restrict__ pred_j,
                                                    float* __restrict__ pred, int Q) {
    int wave = (int)((blockIdx.x * 256 + threadIdx.x) >> 6);
    int lane = threadIdx.x & 63;
    if (wave >= Q) return;
    int r = qrow[wave], c = qcol[wave];
    int yr = y[r], yc = y[c];                  // uniform -> broadcast loads
    int g = lane >> 4;                         // 0: emb[r,yr] 1: emb[c,yr] 2: emb[r,yc] 3: emb[c,yc]
    int t = lane & 15;
    int node = (g & 1) ? c : r;
    int head = (g >> 1) ? yc : yr;
    const float4* p = (const float4*)(emb + (size_t)node * 512 + head * 64);
    float4 v = p[t];
    float4 o;
    o.x = __shfl_xor(v.x, 16, 64);
    o.y = __shfl_xor(v.y, 16, 64);
    o.z = __shfl_xor(v.z, 16, 64);
    o.w = __shfl_xor(v.w, 16, 64);
    float s = v.x * o.x + v.y * o.y + v.z * o.z + v.w * o.w;
#pragma unroll
    for (int off = 8; off >= 1; off >>= 1) s += __shfl_xor(s, off, 64);
    float other = __shfl_xor(s, 32, 64);       // lane0: pj
    if (lane == 0) {
        pred_i[wave] = s;
        pred_j[wave] = other;
        pred[wave]   = 0.5f * (s + other);
    }
}

extern "C" void kernel_launch(void* const* d_in, const int* in_sizes, int n_in,
                              void* d_out, int out_size, void* d_ws, size_t ws_size,
                              hipStream_t stream) {
    const float* x   = (const float*)d_in[0];
    const float* W1  = (const float*)d_in[1];
    const float* b1  = (const float*)d_in[2];
    const float* W2  = (const float*)d_in[3];
    const float* b2  = (const float*)d_in[4];
    const int* edge  = (const int*)d_in[5];
    const int* qedge = (const int*)d_in[6];
    const int* y     = (const int*)d_in[7];

    const int N = in_sizes[0] / 128;   // 100000
    const int E = in_sizes[5] / 2;     // 1600000
    const int Q = in_sizes[6] / 2;     // 400000

    float* out     = (float*)d_out;
    float* hiddens = out;                         // [N,128]
    float* emb     = out + (size_t)N * 128;       // [N,512]
    float* pred_i  = emb + (size_t)N * 512;       // [Q]
    float* pred_j  = pred_i + Q;                  // [Q]
    float* pred    = pred_j + Q;                  // [Q]

    // workspace carve (256B aligned)
    char* w = (char*)d_ws;
    auto alloc = [&](size_t bytes) { char* p = w; w += (bytes + 255) & ~(size_t)255; return p; };
    int*    cnt      = (int*)alloc((size_t)N * 4);
    int*    row_ptr  = (int*)alloc((size_t)(N + 1) * 4);
    int*    cursor   = (int*)alloc((size_t)N * 4);
    float*  dinv     = (float*)alloc((size_t)N * 4);
    int2*   csr      = (int2*)alloc((size_t)E * 8);           // paired {src, wt}
    int*    blocksum = (int*)alloc(256 * 4);
    int*    blockoff = (int*)alloc(256 * 4);
    __half* tblh     = (__half*)alloc((size_t)N * 128 * 2);   // fp16 gather table (x, then hiddens)
    ushort* aggh     = (ushort*)alloc((size_t)N * 128 * 2);   // 25.6 MB
    ushort* aggl     = (ushort*)alloc((size_t)N * 128 * 2);   // 25.6 MB
    ushort* w1h      = (ushort*)alloc(128 * 128 * 2);
    ushort* w1l      = (ushort*)alloc(128 * 128 * 2);
    ushort* w2h      = (ushort*)alloc(128 * 512 * 2);
    ushort* w2l      = (ushort*)alloc(128 * 512 * 2);

    const int* esrc = edge;         const int* edst = edge + E;
    const int* qrow = qedge;        const int* qcol = qedge + Q;

    const int nb = (N + SCAN_SEG - 1) / SCAN_SEG;   // 196 <= 256

    hipMemsetAsync(cnt, 0, (size_t)N * 4, stream);
    count_kernel<<<dim3((E + 255) / 256), dim3(256), 0, stream>>>(edst, cnt, E);
    blocksum_kernel<<<dim3(nb), dim3(256), 0, stream>>>(cnt, blocksum, N);
    blockscan_kernel<<<dim3(1), dim3(256), 0, stream>>>(blocksum, blockoff, nb, row_ptr, N, E);
    csr_ptr_kernel<<<dim3(nb), dim3(256), 0, stream>>>(cnt, blockoff, row_ptr, cursor, dinv, N);
    tohalf_kernel<<<dim3((N * 32 + 255) / 256), dim3(256), 0, stream>>>(x, tblh, N);
    fill_kernel<<<dim3((E + 255) / 256), dim3(256), 0, stream>>>(esrc, edst, cursor, dinv, csr, E);

    // one-time weight transpose+split (tiny)
    wsplit_kernel<<<dim3((128 * 128 + 255) / 256), dim3(256), 0, stream>>>(W1, w1h, w1l, 128);
    wsplit_kernel<<<dim3((128 * 512 + 255) / 256), dim3(256), 0, stream>>>(W2, w2h, w2l, 512);

    const int mblocks = (N + 127) / 128;   // 782
    const int ablocks = (N + 3) / 4;       // 25000

    // layer 1: aggregate fp16(x), then MFMA GEMM (bias+relu; also emits fp16 hiddens table)
    agg_kernel<<<dim3(ablocks), dim3(256), 0, stream>>>(tblh, row_ptr, csr, dinv, aggh, aggl, N);
    gemm_mfma<<<dim3(1, mblocks), dim3(256), 0, stream>>>(aggh, aggl, w1h, w1l, b1, hiddens,
                                                          tblh, N, 128, 1);

    // layer 2: aggregate fp16(hiddens), then MFMA GEMM with fused bias
    agg_kernel<<<dim3(ablocks), dim3(256), 0, stream>>>(tblh, row_ptr, csr, dinv, aggh, aggl, N);
    gemm_mfma<<<dim3(4, mblocks), dim3(256), 0, stream>>>(aggh, aggl, w2h, w2l, b2, emb,
                                                          nullptr, N, 512, 0);

    query_kernel<<<dim3((Q + 3) / 4), dim3(256), 0, stream>>>(emb, qrow, qcol, y, pred_i, pred_j, pred, Q);
}

// Round 8
// 813.348 us; speedup vs baseline: 1.2189x; 1.0340x over previous
//
#include <hip/hip_runtime.h>
#include <hip/hip_bf16.h>
#include <hip/hip_fp16.h>

// ---------------------------------------------------------------------------
// GNN: hiddens = relu(gcn(x,W1,b1)); emb = gcn(hiddens,W2,b2);
// pred_i/j = <emb[r,y,:],emb[c,y,:]> at head y[r]/y[c].
//
// aggregate-then-transform: A_norm @ (H @ W) = (A_norm @ H) @ W.
// CSR build: count -> 3-phase scan -> fill writes PAIRED {src, wt} int2.
// agg: wave/node, 2x32-lane interleaved edge groups, 4 gathers in flight,
//      FP16 gather table (halves gather bytes; fp32 accumulate), fp16 out.
// GEMM: f16 MFMA, C = A*(Bh+Bl): A single fp16 (2^-11, at the fp16-table
//   noise floor), B split-fp16 (2^-22). 2 MFMA passes (was 3 bf16-split),
//   48KB LDS -> 3 blocks/CU (was 2), staging bytes -25%.
//   128x128 tile, 4 waves (2x2), wave tile 64x64 = 4x4 frags of 16x16x32.
//   gemm1 epilogue emits the fp16 hiddens table for layer-2 agg.
// ---------------------------------------------------------------------------

#define SCAN_SEG 512   // elements per scan block (256 threads x 2)

typedef _Float16 f16x8 __attribute__((ext_vector_type(8)));   // 8 fp16 in 4 VGPRs
typedef _Float16 f16x4 __attribute__((ext_vector_type(4)));   // 8 B
typedef float    f32x4 __attribute__((ext_vector_type(4)));

__global__ void count_kernel(const int* __restrict__ dst, int* __restrict__ cnt, int E) {
    int e = blockIdx.x * blockDim.x + threadIdx.x;
    if (e < E) atomicAdd(&cnt[dst[e]], 1);
}

// phase 1: per-block segment sums (coalesced)
__global__ __launch_bounds__(256) void blocksum_kernel(const int* __restrict__ cnt,
                                                       int* __restrict__ blocksum, int n) {
    __shared__ int red[4];
    int b = blockIdx.x, t = threadIdx.x;
    int i0 = b * SCAN_SEG + t;
    int s = 0;
    if (i0 < n) s += cnt[i0];
    if (i0 + 256 < n) s += cnt[i0 + 256];
#pragma unroll
    for (int off = 32; off >= 1; off >>= 1) s += __shfl_xor(s, off, 64);
    if ((t & 63) == 0) red[t >> 6] = s;
    __syncthreads();
    if (t == 0) blocksum[b] = red[0] + red[1] + red[2] + red[3];
}

// phase 2: exclusive scan of <=256 block sums in one small block
__global__ __launch_bounds__(256) void blockscan_kernel(const int* __restrict__ blocksum,
                                                        int* __restrict__ blockoff, int nb,
                                                        int* __restrict__ row_ptr, int n, int E) {
    __shared__ int s[256];
    int t = threadIdx.x;
    int v = (t < nb) ? blocksum[t] : 0;
    s[t] = v;
    __syncthreads();
    for (int off = 1; off < 256; off <<= 1) {
        int u = (t >= off) ? s[t - off] : 0;
        __syncthreads();
        s[t] += u;
        __syncthreads();
    }
    if (t < nb) blockoff[t] = s[t] - v;   // exclusive
    if (t == 0) row_ptr[n] = E;
}

// phase 3: per-block exclusive scan over its 512-elem segment -> row_ptr/cursor/dinv
__global__ __launch_bounds__(256) void csr_ptr_kernel(const int* __restrict__ cnt,
                                                      const int* __restrict__ blockoff,
                                                      int* __restrict__ row_ptr,
                                                      int* __restrict__ cursor,
                                                      float* __restrict__ dinv, int n) {
    __shared__ int s[256];
    int b = blockIdx.x, t = threadIdx.x;
    int i0 = b * SCAN_SEG + 2 * t;       // thread handles i0, i0+1
    int c0 = (i0     < n) ? cnt[i0]     : 0;
    int c1 = (i0 + 1 < n) ? cnt[i0 + 1] : 0;
    int pair = c0 + c1;
    s[t] = pair;
    __syncthreads();
    for (int off = 1; off < 256; off <<= 1) {
        int u = (t >= off) ? s[t - off] : 0;
        __syncthreads();
        s[t] += u;
        __syncthreads();
    }
    int excl = s[t] - pair + blockoff[b];
    if (i0 < n) {
        row_ptr[i0] = excl;
        cursor[i0]  = excl;
        dinv[i0]    = rsqrtf((float)(c0 + 1));
    }
    if (i0 + 1 < n) {
        row_ptr[i0 + 1] = excl + c0;
        cursor[i0 + 1]  = excl + c0;
        dinv[i0 + 1]    = rsqrtf((float)(c1 + 1));
    }
}

// fill PAIRED csr entries: one 8B store per edge
__global__ void fill_kernel(const int* __restrict__ src, const int* __restrict__ dst,
                            int* __restrict__ cursor, const float* __restrict__ dinv,
                            int2* __restrict__ csr, int E) {
    int e = blockIdx.x * blockDim.x + threadIdx.x;
    if (e < E) {
        int s = src[e], d = dst[e];
        int pos = atomicAdd(&cursor[d], 1);
        csr[pos] = make_int2(s, __float_as_int(dinv[s] * dinv[d]));
    }
}

// x fp32 [N][128] -> fp16 table
__global__ __launch_bounds__(256) void tohalf_kernel(const float* __restrict__ x,
                                                     _Float16* __restrict__ xh, int n) {
    int id = blockIdx.x * 256 + threadIdx.x;   // float4 index
    if (id >= n * 32) return;
    float4 v = ((const float4*)x)[id];
    f16x4 h;
    h[0] = (_Float16)v.x; h[1] = (_Float16)v.y;
    h[2] = (_Float16)v.z; h[3] = (_Float16)v.w;
    ((f16x4*)xh)[id] = h;
}

// W[k][ncols] fp32 -> Wt_h/Wt_l[col][k] fp16 hi/lo (transposed, split). Tiny, once.
__global__ __launch_bounds__(256) void wsplit_kernel(const float* __restrict__ W,
                                                     _Float16* __restrict__ th,
                                                     _Float16* __restrict__ tl, int ncols) {
    int idx = blockIdx.x * 256 + threadIdx.x;   // over 128*ncols
    if (idx >= 128 * ncols) return;
    int col = idx >> 7;
    int k   = idx & 127;
    float v = W[(size_t)k * ncols + col];
    _Float16 h = (_Float16)v;
    th[idx] = h;
    tl[idx] = (_Float16)(v - (float)h);
}

// agg: out[node,f] = fp16( dinv^2*feat[node,f] + sum_e wt[e]*feat[src[e],f] )
// feat is the FP16 table (256B/row). One wave per node; two 32-lane groups
// own alternate edges (interleaved); 4 gathers in flight per group
// (threshold deg>=8 covers ~97% of Poisson(16) -- round-6 lesson).
__global__ __launch_bounds__(256) void agg_kernel(const _Float16* __restrict__ feat,
                                                  const int* __restrict__ row_ptr,
                                                  const int2* __restrict__ csr,
                                                  const float* __restrict__ dinv,
                                                  _Float16* __restrict__ outf, int n) {
    const int w    = threadIdx.x >> 6;         // wave 0..3
    const int lane = threadIdx.x & 63;
    const int node = blockIdx.x * 4 + w;
    if (node >= n) return;
    const int g = lane >> 5;                   // edge-parity group 0/1
    const int c = lane & 31;                   // 4-feat chunk index (covers 128 feats)

    float di = dinv[node];
    float4 acc = make_float4(0.f, 0.f, 0.f, 0.f);
    if (g == 0) {                              // self-loop message
        f16x4 v = ((const f16x4*)(feat + (size_t)node * 128))[c];
        float s2 = di * di;
        acc.x = (float)v[0] * s2; acc.y = (float)v[1] * s2;
        acc.z = (float)v[2] * s2; acc.w = (float)v[3] * s2;
    }

    int e0 = row_ptr[node], e1 = row_ptr[node + 1];
    int e = e0 + g;
    for (; e + 6 < e1; e += 8) {               // 4 edges per group in flight
        int2 p0 = csr[e],     p1 = csr[e + 2];
        int2 p2 = csr[e + 4], p3 = csr[e + 6];
        float w0 = __int_as_float(p0.y), w1 = __int_as_float(p1.y);
        float w2 = __int_as_float(p2.y), w3 = __int_as_float(p3.y);
        f16x4 v0 = ((const f16x4*)(feat + (size_t)p0.x * 128))[c];
        f16x4 v1 = ((const f16x4*)(feat + (size_t)p1.x * 128))[c];
        f16x4 v2 = ((const f16x4*)(feat + (size_t)p2.x * 128))[c];
        f16x4 v3 = ((const f16x4*)(feat + (size_t)p3.x * 128))[c];
        acc.x += (float)v0[0] * w0 + (float)v1[0] * w1 + (float)v2[0] * w2 + (float)v3[0] * w3;
        acc.y += (float)v0[1] * w0 + (float)v1[1] * w1 + (float)v2[1] * w2 + (float)v3[1] * w3;
        acc.z += (float)v0[2] * w0 + (float)v1[2] * w1 + (float)v2[2] * w2 + (float)v3[2] * w3;
        acc.w += (float)v0[3] * w0 + (float)v1[3] * w1 + (float)v2[3] * w2 + (float)v3[3] * w3;
    }
    for (; e < e1; e += 2) {
        int2 p0 = csr[e];
        float w0 = __int_as_float(p0.y);
        f16x4 v0 = ((const f16x4*)(feat + (size_t)p0.x * 128))[c];
        acc.x += (float)v0[0] * w0; acc.y += (float)v0[1] * w0;
        acc.z += (float)v0[2] * w0; acc.w += (float)v0[3] * w0;
    }

    // combine the two edge groups
    acc.x += __shfl_xor(acc.x, 32, 64);
    acc.y += __shfl_xor(acc.y, 32, 64);
    acc.z += __shfl_xor(acc.z, 32, 64);
    acc.w += __shfl_xor(acc.w, 32, 64);

    if (g == 0) {
        f16x4 o;
        o[0] = (_Float16)acc.x; o[1] = (_Float16)acc.y;
        o[2] = (_Float16)acc.z; o[3] = (_Float16)acc.w;
        ((f16x4*)(outf + (size_t)node * 128))[c] = o;
    }
}

// ---------------------------------------------------------------------------
// C[N, 128-col chunk] = X @ W + bias (f16 MFMA, C = A*(Bh+Bl)):
//   X: [N][128] fp16 row-major (agg output); Wth/Wtl: [colG][128] fp16.
// LDS per half-K: [row|col 0..127][k 0..63] fp16 (128B row stride),
//   16B-chunk XOR swizzle: byte ^ ((row&7)<<4), write AND read sides.
// Fragment maps (mfma_f32_16x16x32_f16):
//   A: row=lane&15, k=(lane>>4)*8+j ; B: col=lane&15, same k
//   C/D: col=lane&15, row=(lane>>4)*4+reg   [dtype-independent, m89/m121]
// 48KB LDS -> 3 blocks/CU (12 waves). If tbl!=nullptr (layer 1): also
// write the fp16 table of the result for layer-2 agg.
// ---------------------------------------------------------------------------
__global__ __launch_bounds__(256, 3) void gemm_mfma(const _Float16* __restrict__ X_g,
                                                    const _Float16* __restrict__ Wth_g,
                                                    const _Float16* __restrict__ Wtl_g,
                                                    const float* __restrict__ bias,
                                                    float* __restrict__ C,
                                                    _Float16* __restrict__ tbl,
                                                    int N, int ldw, int do_relu) {
    __shared__ _Float16 Xs[128 * 64];   // 16 KB each, 48 KB total -> 3 blocks/CU
    __shared__ _Float16 Wh[128 * 64];
    __shared__ _Float16 Wl[128 * 64];

    const int tid  = threadIdx.x;
    const int lane = tid & 63;
    const int wv   = tid >> 6;        // wave 0..3
    const int wr   = wv >> 1;         // wave row 0..1 (64 rows each)
    const int wc   = wv & 1;          // wave col 0..1 (64 cols each)
    const int lr   = lane & 15;
    const int lk   = lane >> 4;       // k-group 0..3
    const int row0   = blockIdx.y * 128;
    const int colOff = blockIdx.x * 128;

    f32x4 acc[4][4];
#pragma unroll
    for (int i = 0; i < 4; ++i)
#pragma unroll
        for (int j = 0; j < 4; ++j)
            acc[i][j] = (f32x4){0.f, 0.f, 0.f, 0.f};

    for (int ph = 0; ph < 2; ++ph) {
        if (ph) __syncthreads();      // prev compute done before overwrite

        // ---- stage X half-tile: swizzled 16B copies (1024 chunks) ----
#pragma unroll
        for (int q = 0; q < 4; ++q) {
            int cidx = tid + 256 * q;            // 16B-chunk id 0..1023
            int row  = cidx >> 3;                // 0..127
            int kch  = cidx & 7;                 // 16B chunk within 64-k half
            int gr   = row0 + row; if (gr >= N) gr = N - 1;
            size_t ge = (size_t)gr * 128 + ph * 64 + kch * 8;
            int lb = row * 128 + ((kch * 16) ^ ((row & 7) << 4));
            *(int4*)((char*)Xs + lb) = *(const int4*)(X_g + ge);
        }
        // ---- stage W half-tiles (already transposed/split in global) ----
#pragma unroll
        for (int q = 0; q < 4; ++q) {
            int cidx = tid + 256 * q;
            int col  = cidx >> 3;
            int kch  = cidx & 7;
            size_t ge = (size_t)(colOff + col) * 128 + ph * 64 + kch * 8;
            int lb = col * 128 + ((kch * 16) ^ ((col & 7) << 4));
            *(int4*)((char*)Wh + lb) = *(const int4*)(Wth_g + ge);
            *(int4*)((char*)Wl + lb) = *(const int4*)(Wtl_g + ge);
        }
        __syncthreads();

        // ---- compute: 2 x K=32 chunks per phase ----
#pragma unroll
        for (int kk = 0; kk < 2; ++kk) {
            const int kb = (kk * 32 + lk * 8) * 2;    // byte offset pre-swizzle
            f16x8 a[4], bh[4], bl[4];
#pragma unroll
            for (int mi = 0; mi < 4; ++mi) {
                int row  = wr * 64 + mi * 16 + lr;
                int byte = row * 128 + (kb ^ ((row & 7) << 4));
                a[mi] = *(const f16x8*)((const char*)Xs + byte);
            }
#pragma unroll
            for (int ni = 0; ni < 4; ++ni) {
                int col  = wc * 64 + ni * 16 + lr;
                int byte = col * 128 + (kb ^ ((col & 7) << 4));
                bh[ni] = *(const f16x8*)((const char*)Wh + byte);
                bl[ni] = *(const f16x8*)((const char*)Wl + byte);
            }
#pragma unroll
            for (int mi = 0; mi < 4; ++mi)
#pragma unroll
                for (int ni = 0; ni < 4; ++ni) {
                    acc[mi][ni] = __builtin_amdgcn_mfma_f32_16x16x32_f16(
                        a[mi], bh[ni], acc[mi][ni], 0, 0, 0);
                    acc[mi][ni] = __builtin_amdgcn_mfma_f32_16x16x32_f16(
                        a[mi], bl[ni], acc[mi][ni], 0, 0, 0);
                }
        }
    }

    // ---- epilogue: bias (+relu), scalar stores (64B/quarter-wave segments) ----
#pragma unroll
    for (int ni = 0; ni < 4; ++ni) {
        int col = colOff + wc * 64 + ni * 16 + lr;
        float bv = bias[col];
#pragma unroll
        for (int mi = 0; mi < 4; ++mi) {
            int rbase = row0 + wr * 64 + mi * 16 + (lane >> 4) * 4;
#pragma unroll
            for (int r = 0; r < 4; ++r) {
                int row = rbase + r;
                if (row < N) {
                    float v = acc[mi][ni][r] + bv;
                    if (do_relu) v = fmaxf(v, 0.f);
                    C[(size_t)row * ldw + col] = v;
                    if (tbl) tbl[(size_t)row * 128 + col] = (_Float16)v;
                }
            }
        }
    }
}

// one wave per query edge; 4 lane-groups of 16 gather the 4 head-vectors in
// ONE float4 issue; shfl_xor(16) pairs er*ec; 16-lane reduce; shfl_xor(32)
// marries pi (lanes 0..31) with pj (lanes 32..63).
__global__ __launch_bounds__(256) void query_kernel(const float* __restrict__ emb,
                                                    const int* __restrict__ qrow,
                                                    const int* __restrict__ qcol,
                                                    const int* __restrict__ y,
                                                    float* __restrict__ pred_i,
                                                    float* __restrict__ pred_j,
                                                    float* __restrict__ pred, int Q) {
    int wave = (int)((blockIdx.x * 256 + threadIdx.x) >> 6);
    int lane = threadIdx.x & 63;
    if (wave >= Q) return;
    int r = qrow[wave], c = qcol[wave];
    int yr = y[r], yc = y[c];                  // uniform -> broadcast loads
    int g = lane >> 4;                         // 0: emb[r,yr] 1: emb[c,yr] 2: emb[r,yc] 3: emb[c,yc]
    int t = lane & 15;
    int node = (g & 1) ? c : r;
    int head = (g >> 1) ? yc : yr;
    const float4* p = (const float4*)(emb + (size_t)node * 512 + head * 64);
    float4 v = p[t];
    float4 o;
    o.x = __shfl_xor(v.x, 16, 64);
    o.y = __shfl_xor(v.y, 16, 64);
    o.z = __shfl_xor(v.z, 16, 64);
    o.w = __shfl_xor(v.w, 16, 64);
    float s = v.x * o.x + v.y * o.y + v.z * o.z + v.w * o.w;
#pragma unroll
    for (int off = 8; off >= 1; off >>= 1) s += __shfl_xor(s, off, 64);
    float other = __shfl_xor(s, 32, 64);       // lane0: pj
    if (lane == 0) {
        pred_i[wave] = s;
        pred_j[wave] = other;
        pred[wave]   = 0.5f * (s + other);
    }
}

extern "C" void kernel_launch(void* const* d_in, const int* in_sizes, int n_in,
                              void* d_out, int out_size, void* d_ws, size_t ws_size,
                              hipStream_t stream) {
    const float* x   = (const float*)d_in[0];
    const float* W1  = (const float*)d_in[1];
    const float* b1  = (const float*)d_in[2];
    const float* W2  = (const float*)d_in[3];
    const float* b2  = (const float*)d_in[4];
    const int* edge  = (const int*)d_in[5];
    const int* qedge = (const int*)d_in[6];
    const int* y     = (const int*)d_in[7];

    const int N = in_sizes[0] / 128;   // 100000
    const int E = in_sizes[5] / 2;     // 1600000
    const int Q = in_sizes[6] / 2;     // 400000

    float* out     = (float*)d_out;
    float* hiddens = out;                         // [N,128]
    float* emb     = out + (size_t)N * 128;       // [N,512]
    float* pred_i  = emb + (size_t)N * 512;       // [Q]
    float* pred_j  = pred_i + Q;                  // [Q]
    float* pred    = pred_j + Q;                  // [Q]

    // workspace carve (256B aligned)
    char* w = (char*)d_ws;
    auto alloc = [&](size_t bytes) { char* p = w; w += (bytes + 255) & ~(size_t)255; return p; };
    int*      cnt      = (int*)alloc((size_t)N * 4);
    int*      row_ptr  = (int*)alloc((size_t)(N + 1) * 4);
    int*      cursor   = (int*)alloc((size_t)N * 4);
    float*    dinv     = (float*)alloc((size_t)N * 4);
    int2*     csr      = (int2*)alloc((size_t)E * 8);           // paired {src, wt}
    int*      blocksum = (int*)alloc(256 * 4);
    int*      blockoff = (int*)alloc(256 * 4);
    _Float16* tblh     = (_Float16*)alloc((size_t)N * 128 * 2); // fp16 gather table
    _Float16* aggf     = (_Float16*)alloc((size_t)N * 128 * 2); // fp16 agg output
    _Float16* w1h      = (_Float16*)alloc(128 * 128 * 2);
    _Float16* w1l      = (_Float16*)alloc(128 * 128 * 2);
    _Float16* w2h      = (_Float16*)alloc(128 * 512 * 2);
    _Float16* w2l      = (_Float16*)alloc(128 * 512 * 2);

    const int* esrc = edge;         const int* edst = edge + E;
    const int* qrow = qedge;        const int* qcol = qedge + Q;

    const int nb = (N + SCAN_SEG - 1) / SCAN_SEG;   // 196 <= 256

    hipMemsetAsync(cnt, 0, (size_t)N * 4, stream);
    count_kernel<<<dim3((E + 255) / 256), dim3(256), 0, stream>>>(edst, cnt, E);
    blocksum_kernel<<<dim3(nb), dim3(256), 0, stream>>>(cnt, blocksum, N);
    blockscan_kernel<<<dim3(1), dim3(256), 0, stream>>>(blocksum, blockoff, nb, row_ptr, N, E);
    csr_ptr_kernel<<<dim3(nb), dim3(256), 0, stream>>>(cnt, blockoff, row_ptr, cursor, dinv, N);
    tohalf_kernel<<<dim3((N * 32 + 255) / 256), dim3(256), 0, stream>>>(x, tblh, N);
    fill_kernel<<<dim3((E + 255) / 256), dim3(256), 0, stream>>>(esrc, edst, cursor, dinv, csr, E);

    // one-time weight transpose+split (tiny)
    wsplit_kernel<<<dim3((128 * 128 + 255) / 256), dim3(256), 0, stream>>>(W1, w1h, w1l, 128);
    wsplit_kernel<<<dim3((128 * 512 + 255) / 256), dim3(256), 0, stream>>>(W2, w2h, w2l, 512);

    const int mblocks = (N + 127) / 128;   // 782
    const int ablocks = (N + 3) / 4;       // 25000

    // layer 1: aggregate fp16(x), then f16 MFMA GEMM (bias+relu; emits fp16 hiddens table)
    agg_kernel<<<dim3(ablocks), dim3(256), 0, stream>>>(tblh, row_ptr, csr, dinv, aggf, N);
    gemm_mfma<<<dim3(1, mblocks), dim3(256), 0, stream>>>(aggf, w1h, w1l, b1, hiddens,
                                                          tblh, N, 128, 1);

    // layer 2: aggregate fp16(hiddens), then f16 MFMA GEMM with fused bias
    agg_kernel<<<dim3(ablocks), dim3(256), 0, stream>>>(tblh, row_ptr, csr, dinv, aggf, N);
    gemm_mfma<<<dim3(4, mblocks), dim3(256), 0, stream>>>(aggf, w2h, w2l, b2, emb,
                                                          nullptr, N, 512, 0);

    query_kernel<<<dim3((Q + 3) / 4), dim3(256), 0, stream>>>(emb, qrow, qcol, y, pred_i, pred_j, pred, Q);
}